// Round 16
// baseline (14899.855 us; speedup 1.0000x reference)
//
#include <hip/hip_runtime.h>

// APDL_RNN: allpass-delay LSTM. B=32, T=8192, I=1, H=256, OS_FACTOR=1.5 -> coeff=1/3.
// R16 = R14 geometry (256 WGs = 32 batches x 8 octet members; 512 thr/WG; 32 units/WG;
// K-split x4, 16 pinned floatx4/thread) + ALIAS-PROOF bounded fast path:
//   pubf slot = 16B [tag32 | vb | pb | tag32]; probe validates FULL 32-bit tags
//   (R15 failed: 9-bit tag aliased with 512-step-old lazily-written-back values on
//   the sc0/IC path -> stale accepted -> absmax 1.98e-2). vb/pb are the SAME
//   self-tagged bits as the agent path -> bit-identical math on either path.
//   Reader: <=2 bounded sc0 dwordx4 probes (own vmcnt(0) each), else proven agent
//   spin; 8-miss hysteresis latch. Deadlock- and alias-impossible by construction.
// Agent protocol itself UNCHANGED (R5/R12/R14-proven): serial 8B atomics, tag in
// low 9 mantissa bits, 2 units/slot, parity-dbuf hs2, ONE barrier/step,
// publish right after allpass-h, own-chunk LDS shortcut.

#define Bn 32
#define Tn 8192
#define Hn 256
#define QP 72  // LDS stride per K-quarter: banks 0/8/16/24 across q -> conflict-free

typedef float floatx4 __attribute__((ext_vector_type(4)));
typedef unsigned int uintx4 __attribute__((ext_vector_type(4)));

static constexpr float kCoeff = 1.0f / 3.0f;  // (1-alpha)/(1+alpha), alpha=0.5

__device__ __forceinline__ float sigf(float x) {
  return __builtin_amdgcn_rcpf(1.0f + __expf(-x));
}
__device__ __forceinline__ float tanhf_fast(float x) {
  return 1.0f - 2.0f * __builtin_amdgcn_rcpf(1.0f + __expf(2.0f * x));
}
__device__ __forceinline__ float pick4(int d, float v0, float v1, float v2, float v3) {
  float r = (d == 0) ? v0 : v1;
  r = (d == 2) ? v2 : r;
  r = (d == 3) ? v3 : r;
  return r;
}
// embed tag in low 9 mantissa bits (round-to-nearest on the kept part)
__device__ __forceinline__ unsigned tagf(float v, unsigned tg) {
  return ((__float_as_uint(v) + 256u) & ~511u) | tg;
}
__device__ __forceinline__ int pidx(int u) { return u + ((u >> 6) << 3); }  // pad map

// d_ws: uintx4 pubf[32][2][128] @0      (16B slots, full-tag sc0/L2 fast path)
//       ull    pubs[32][2][128] @131072 (8B slots, agent/IC safe path)
// total 196608 B; re-zeroed every launch so stale tags (tag=0) never match t>=1.
__global__ void init_ws(unsigned int* ws) {
  int i = blockIdx.x * 256 + threadIdx.x;
  if (i < 49152) ws[i] = 0;
}

#define LOADW(i) floatx4 w##i = *(const floatx4*)(wrow + 4 * (i))
#define PINW(i) asm volatile("" : "+v"(w##i))
#define ACC8(i, j, K)                                           \
  {                                                             \
    floatx4 p = *(const floatx4*)&hsp[(K)];                     \
    floatx4 q = *(const floatx4*)&hsp[(K) + 4];                 \
    a0 = fmaf(w##i[0], p[0], a0); a1 = fmaf(w##i[1], p[1], a1); \
    a2 = fmaf(w##i[2], p[2], a2); a3 = fmaf(w##i[3], p[3], a3); \
    a4 = fmaf(w##j[0], q[0], a4); a5 = fmaf(w##j[1], q[1], a5); \
    a6 = fmaf(w##j[2], q[2], a6); a7 = fmaf(w##j[3], q[3], a7); \
  }

__global__ __launch_bounds__(512, 2) void apdl_rnn(
    const float* __restrict__ x, const float* __restrict__ W_ih,
    const float* __restrict__ W_hh, const float* __restrict__ b_ih,
    const float* __restrict__ b_hh, float* __restrict__ out,
    uintx4* __restrict__ pubf, unsigned long long* __restrict__ pubs) {
  const int bid = blockIdx.x;
  const int w = bid >> 5;      // octet member 0..7
  const int b = bid & 31;      // batch
  const int tid = (int)threadIdx.x;
  const int q = tid & 3;       // K-quarter: k in [q*64, q*64+64)
  const int r = tid >> 2;      // row index 0..127
  const int g = r & 3;         // gate: 0=i 1=f 2=g 3=o
  const int ul = r >> 2;       // local unit 0..31
  const int u = w * 32 + ul;   // global unit 0..255
  const int row = g * Hn + u;

  __shared__ __align__(16) float xs[Tn];          // this batch's x sequence, 32KB
  __shared__ __align__(16) float hs2[2][4 * QP];  // parity-dbuf quarter-padded ap_h

  for (int i = tid; i < Tn; i += 512) xs[i] = x[b * Tn + i];

  // this thread's quarter-row: 16 x floatx4, pinned once (unified VGPR/AGPR file)
  const float* wrow = W_hh + row * Hn + q * 64;
  LOADW(0);  LOADW(1);  LOADW(2);  LOADW(3);  LOADW(4);  LOADW(5);  LOADW(6);  LOADW(7);
  LOADW(8);  LOADW(9);  LOADW(10); LOADW(11); LOADW(12); LOADW(13); LOADW(14); LOADW(15);
  asm volatile("s_waitcnt vmcnt(0)" ::: "memory");
  PINW(0);  PINW(1);  PINW(2);  PINW(3);  PINW(4);  PINW(5);  PINW(6);  PINW(7);
  PINW(8);  PINW(9);  PINW(10); PINW(11); PINW(12); PINW(13); PINW(14); PINW(15);

  const float wih = W_ih[row];
  const float bias = b_ih[row] + b_hh[row];

  uintx4* myf = pubf + b * 2 * 128;              // [parity][slot], 16B fast slots
  unsigned long long* mys = pubs + b * 2 * 128;  // [parity][slot], 8B agent slots

  // pollers: lanes 0..111, one remote slot (2 units) each; own 16 slots
  // arrive via the publisher's LDS shortcut (no IC trip).
  const bool poller = (tid < 112);
  const int slot = poller ? (tid < w * 16 ? tid : tid + 16) : 0;  // skip own chunk

  int fmiss = 0;        // consecutive steps where fast probes all missed
  bool fastok = true;   // hysteresis latch for the sc0 fast path

  float s1_h = 0.f, s1_c = 0.f, ap_h = 0.f, ap_c = 0.f;

  for (int t = 0; t < Tn; ++t) {
    // ---- acquire ap_h(t) for remote units ----
    if (t == 0) {
      if (tid < 128) {
        *(float2*)&hs2[0][pidx(2 * tid)] = make_float2(0.f, 0.f);  // ap(0) = 0
      }
    } else if (poller) {
      const int pp = (t & 1) * 128 + slot;
      const unsigned tg9 = (unsigned)t & 511u;
      unsigned vb, pb;
      bool got = false;
      if (fastok) {
        // bounded probes, FULL 32-bit tag check (word0==t && word3==t).
        // Stale write-backs carry old full tags -> can never match. Torn 8B
        // halves each carry their own tag word -> tearing detected.
#pragma unroll
        for (int k = 0; k < 2; ++k) {
          if (!got) {
            uintx4 v;
            asm volatile("global_load_dwordx4 %0, %1, off sc0\n\ts_waitcnt vmcnt(0)"
                         : "=v"(v) : "v"(myf + pp) : "memory");
            if (v.x == (unsigned)t && v.w == (unsigned)t) {
              vb = v.y; pb = v.z; got = true;
            }
          }
        }
        if (got) fmiss = 0;
        else if (++fmiss >= 8) fastok = false;  // cross-XCD pair: stop probing
      }
      if (!got) {
        // proven agent/IC spin (R5/R12): always succeeds; same value bits
        unsigned long long pk;
        do {
          pk = __hip_atomic_load(mys + pp, __ATOMIC_RELAXED, __HIP_MEMORY_SCOPE_AGENT);
          vb = (unsigned)pk; pb = (unsigned)(pk >> 32);
        } while (((vb ^ tg9) & 511u) | ((pb ^ tg9) & 511u));
      }
      *(float2*)&hs2[t & 1][pidx(2 * slot)] =
          make_float2(__uint_as_float(vb), __uint_as_float(pb));
    }
    __syncthreads();  // single barrier per step (parity dbuf)

    // ---- quarter-row dot: 64 fp32 MACs, weights register-resident ----
    const float* hsp = &hs2[t & 1][q * QP];
    float a0 = 0.f, a1 = 0.f, a2 = 0.f, a3 = 0.f;
    float a4 = 0.f, a5 = 0.f, a6 = 0.f, a7 = 0.f;
    ACC8(0, 1, 0);   ACC8(2, 3, 8);   ACC8(4, 5, 16);  ACC8(6, 7, 24);
    ACC8(8, 9, 32);  ACC8(10, 11, 40); ACC8(12, 13, 48); ACC8(14, 15, 56);
    float qd = ((a0 + a1) + (a2 + a3)) + ((a4 + a5) + (a6 + a7));
    float d0 = qd + __shfl_xor(qd, 1);   // K-combine butterfly
    float dot = d0 + __shfl_xor(d0, 2);
    float raw = dot + xs[t] * wih + bias;

    // ---- activate own gate, exchange across the 4 gates (16-lane unit group) ----
    float act = (g == 2) ? tanhf_fast(raw) : sigf(raw);
    float v1 = __shfl_xor(act, 4);   // gate g^1
    float v2 = __shfl_xor(act, 8);   // gate g^2
    float v3 = __shfl_xor(act, 12);  // gate g^3
    float ai = pick4(g,     act, v1, v2, v3);  // sigmoid(i)
    float af = pick4(g ^ 1, act, v1, v2, v3);  // sigmoid(f)
    float ag = pick4(g ^ 2, act, v1, v2, v3);  // tanh(g)
    float ao = pick4(g ^ 3, act, v1, v2, v3);  // sigmoid(o)

    float c_new = af * ap_c + ai * ag;
    float h_new = ao * tanhf_fast(c_new);

    if (t < Tn - 1) {
      // ---- allpass h-update + dual publish FIRST (latency-critical) ----
      float nh = kCoeff * (h_new - ap_h) + s1_h;
      unsigned vb = tagf(nh, (unsigned)(t + 1) & 511u);  // self-tagged bits
      unsigned pb = __shfl_xor(vb, 16);                  // partner unit's bits
      if ((tid & 31) == 12) {  // g==3,q==0 of even local unit: one per slot
        const int s = w * 16 + (tid >> 5);  // global slot = u/2
        const int pp = ((t + 1) & 1) * 128 + s;
        uintx4 fv;
        fv.x = (unsigned)(t + 1); fv.y = vb; fv.z = pb; fv.w = (unsigned)(t + 1);
        asm volatile("global_store_dwordx4 %0, %1, off sc0"
                     :: "v"(myf + pp), "v"(fv) : "memory");  // fast: writer L2
        unsigned long long pk = (unsigned long long)vb |
                                ((unsigned long long)pb << 32);
        __hip_atomic_store(mys + pp, pk, __ATOMIC_RELAXED,
                           __HIP_MEMORY_SCOPE_AGENT);        // safe: IC (proven)
        *(float2*)&hs2[(t + 1) & 1][pidx(2 * s)] =           // own WG: LDS shortcut
            make_float2(__uint_as_float(vb), __uint_as_float(pb));
      }
      float nc = kCoeff * (c_new - ap_c) + s1_c;
      s1_h = h_new; s1_c = c_new; ap_h = nh; ap_c = nc;
    } else {
      if (g == 0 && q == 0)      out[201326592 + b * 512 + u] = ap_h;        // ap_final h
      else if (g == 1 && q == 0) out[201326592 + b * 512 + 256 + u] = ap_c;  // ap_final c
    }

    // ---- outputs: (y, states_h, states_c) fp32, fire-and-forget ----
    int o = (b * Tn + t) * Hn + u;
    if (q == 0) {
      if (g == 0)      out[o] = h_new;             // y
      else if (g == 2) out[67108864 + o] = h_new;  // states h
      else if (g == 1) out[134217728 + o] = c_new; // states c
    }
    // no trailing barrier: parity dbuf + publish-after-barrier make it safe
  }
}

extern "C" void kernel_launch(void* const* d_in, const int* in_sizes, int n_in,
                              void* d_out, int out_size, void* d_ws, size_t ws_size,
                              hipStream_t stream) {
  const float* x = (const float*)d_in[0];
  const float* W_ih = (const float*)d_in[1];
  const float* W_hh = (const float*)d_in[2];
  const float* b_ih = (const float*)d_in[3];
  const float* b_hh = (const float*)d_in[4];
  float* out = (float*)d_out;
  uintx4* pubf = (uintx4*)d_ws;
  unsigned long long* pubs = (unsigned long long*)((char*)d_ws + 131072);

  init_ws<<<192, 256, 0, stream>>>((unsigned int*)d_ws);  // reset both tag buffers
  apdl_rnn<<<256, 512, 0, stream>>>(x, W_ih, W_hh, b_ih, b_hh, out, pubf, pubs);
}

// Round 17
// 9580.703 us; speedup vs baseline: 1.5552x; 1.5552x over previous
//
#include <hip/hip_runtime.h>

// APDL_RNN: allpass-delay LSTM. B=32, T=8192, I=1, H=256, OS_FACTOR=1.5 -> coeff=1/3.
// R17 = exact R14 revert (proven 8.79 ms). 256 WGs = 32 batches x 8 OCTET members;
// 512 threads/WG (8 waves), 1 WG/CU. Each WG owns 32 units (128 gate rows); each row
// K-split x4: 64 fp32 weights/thread as 16 pinned floatx4.
//
// Final sync protocol (R5-R16, 9-experiment-validated; all variants regressed):
// serial 8B __hip_atomic_{store,load}(AGENT) only; self-tagged packed pairs (tag in
// low 9 mantissa bits, 2 units / 8B slot); parity-dbuf hs2; ONE barrier/step;
// publish right after allpass-h; own-chunk via LDS shortcut.
// Step budget: ~2576 cyc = IC publish->observe (~1800, irreducible: R7/R8/R10/R12/
// R13/R15/R16 all flat-or-worse) + compute (~700, dot at the 256-cyc/CU hardware
// floor: 8.4M MACs/step / 32768 FMA lanes).

#define Bn 32
#define Tn 8192
#define Hn 256
#define QP 72  // LDS stride per K-quarter: banks 0/8/16/24 across q -> conflict-free

typedef float floatx4 __attribute__((ext_vector_type(4)));

static constexpr float kCoeff = 1.0f / 3.0f;  // (1-alpha)/(1+alpha), alpha=0.5

__device__ __forceinline__ float sigf(float x) {
  return __builtin_amdgcn_rcpf(1.0f + __expf(-x));
}
__device__ __forceinline__ float tanhf_fast(float x) {
  return 1.0f - 2.0f * __builtin_amdgcn_rcpf(1.0f + __expf(2.0f * x));
}
__device__ __forceinline__ float pick4(int d, float v0, float v1, float v2, float v3) {
  float r = (d == 0) ? v0 : v1;
  r = (d == 2) ? v2 : r;
  r = (d == 3) ? v3 : r;
  return r;
}
// embed tag in low 9 mantissa bits (round-to-nearest on the kept part)
__device__ __forceinline__ unsigned tagf(float v, unsigned tg) {
  return ((__float_as_uint(v) + 256u) & ~511u) | tg;
}
__device__ __forceinline__ int pidx(int u) { return u + ((u >> 6) << 3); }  // pad map

// d_ws: ull pub[32][2][128] = 65536 B (2 self-tagged fp32 per slot); re-zeroed
// every launch so stale tags can't match.
__global__ void init_ws(unsigned int* ws) {
  int i = blockIdx.x * 256 + threadIdx.x;
  if (i < 16384) ws[i] = 0;
}

#define LOADW(i) floatx4 w##i = *(const floatx4*)(wrow + 4 * (i))
#define PINW(i) asm volatile("" : "+v"(w##i))
#define ACC8(i, j, K)                                           \
  {                                                             \
    floatx4 p = *(const floatx4*)&hsp[(K)];                     \
    floatx4 q = *(const floatx4*)&hsp[(K) + 4];                 \
    a0 = fmaf(w##i[0], p[0], a0); a1 = fmaf(w##i[1], p[1], a1); \
    a2 = fmaf(w##i[2], p[2], a2); a3 = fmaf(w##i[3], p[3], a3); \
    a4 = fmaf(w##j[0], q[0], a4); a5 = fmaf(w##j[1], q[1], a5); \
    a6 = fmaf(w##j[2], q[2], a6); a7 = fmaf(w##j[3], q[3], a7); \
  }

__global__ __launch_bounds__(512, 2) void apdl_rnn(
    const float* __restrict__ x, const float* __restrict__ W_ih,
    const float* __restrict__ W_hh, const float* __restrict__ b_ih,
    const float* __restrict__ b_hh, float* __restrict__ out,
    unsigned long long* __restrict__ pub) {
  const int bid = blockIdx.x;
  const int w = bid >> 5;      // octet member 0..7
  const int b = bid & 31;      // batch
  const int tid = (int)threadIdx.x;
  const int q = tid & 3;       // K-quarter: k in [q*64, q*64+64)
  const int r = tid >> 2;      // row index 0..127
  const int g = r & 3;         // gate: 0=i 1=f 2=g 3=o
  const int ul = r >> 2;       // local unit 0..31
  const int u = w * 32 + ul;   // global unit 0..255
  const int row = g * Hn + u;

  __shared__ __align__(16) float xs[Tn];          // this batch's x sequence, 32KB
  __shared__ __align__(16) float hs2[2][4 * QP];  // parity-dbuf quarter-padded ap_h

  for (int i = tid; i < Tn; i += 512) xs[i] = x[b * Tn + i];

  // this thread's quarter-row: 16 x floatx4, pinned once (unified VGPR/AGPR file)
  const float* wrow = W_hh + row * Hn + q * 64;
  LOADW(0);  LOADW(1);  LOADW(2);  LOADW(3);  LOADW(4);  LOADW(5);  LOADW(6);  LOADW(7);
  LOADW(8);  LOADW(9);  LOADW(10); LOADW(11); LOADW(12); LOADW(13); LOADW(14); LOADW(15);
  asm volatile("s_waitcnt vmcnt(0)" ::: "memory");
  PINW(0);  PINW(1);  PINW(2);  PINW(3);  PINW(4);  PINW(5);  PINW(6);  PINW(7);
  PINW(8);  PINW(9);  PINW(10); PINW(11); PINW(12); PINW(13); PINW(14); PINW(15);

  const float wih = W_ih[row];
  const float bias = b_ih[row] + b_hh[row];

  unsigned long long* mypub = pub + b * 2 * 128;  // [parity][slot]; slot = unit/2

  // pollers: lanes 0..111, one remote 8B slot (2 units) each; own 16 slots
  // arrive via the publisher's LDS shortcut (no IC trip).
  const bool poller = (tid < 112);
  const int slot = poller ? (tid < w * 16 ? tid : tid + 16) : 0;  // skip own chunk

  float s1_h = 0.f, s1_c = 0.f, ap_h = 0.f, ap_c = 0.f;

  for (int t = 0; t < Tn; ++t) {
    // ---- acquire ap_h(t) for remote units: serial agent poll (proven) ----
    if (t == 0) {
      if (tid < 128) {
        *(float2*)&hs2[0][pidx(2 * tid)] = make_float2(0.f, 0.f);  // ap(0) = 0
      }
    } else if (poller) {
      const unsigned long long* pa = mypub + (t & 1) * 128 + slot;
      const unsigned tg = (unsigned)t & 511u;
      unsigned long long pk;
      unsigned lo, hi;
      do {
        pk = __hip_atomic_load(pa, __ATOMIC_RELAXED, __HIP_MEMORY_SCOPE_AGENT);
        lo = (unsigned)pk; hi = (unsigned)(pk >> 32);
      } while (((lo ^ tg) & 511u) | ((hi ^ tg) & 511u));
      *(float2*)&hs2[t & 1][pidx(2 * slot)] =
          make_float2(__uint_as_float(lo), __uint_as_float(hi));
    }
    __syncthreads();  // single barrier per step (parity dbuf)

    // ---- quarter-row dot: 64 fp32 MACs, weights register-resident ----
    const float* hsp = &hs2[t & 1][q * QP];
    float a0 = 0.f, a1 = 0.f, a2 = 0.f, a3 = 0.f;
    float a4 = 0.f, a5 = 0.f, a6 = 0.f, a7 = 0.f;
    ACC8(0, 1, 0);   ACC8(2, 3, 8);   ACC8(4, 5, 16);  ACC8(6, 7, 24);
    ACC8(8, 9, 32);  ACC8(10, 11, 40); ACC8(12, 13, 48); ACC8(14, 15, 56);
    float qd = ((a0 + a1) + (a2 + a3)) + ((a4 + a5) + (a6 + a7));
    float d0 = qd + __shfl_xor(qd, 1);   // K-combine butterfly
    float dot = d0 + __shfl_xor(d0, 2);
    float raw = dot + xs[t] * wih + bias;

    // ---- activate own gate, exchange across the 4 gates (16-lane unit group) ----
    float act = (g == 2) ? tanhf_fast(raw) : sigf(raw);
    float v1 = __shfl_xor(act, 4);   // gate g^1
    float v2 = __shfl_xor(act, 8);   // gate g^2
    float v3 = __shfl_xor(act, 12);  // gate g^3
    float ai = pick4(g,     act, v1, v2, v3);  // sigmoid(i)
    float af = pick4(g ^ 1, act, v1, v2, v3);  // sigmoid(f)
    float ag = pick4(g ^ 2, act, v1, v2, v3);  // tanh(g)
    float ao = pick4(g ^ 3, act, v1, v2, v3);  // sigmoid(o)

    float c_new = af * ap_c + ai * ag;
    float h_new = ao * tanhf_fast(c_new);

    if (t < Tn - 1) {
      // ---- allpass h-update + packed publish FIRST (latency-critical) ----
      float nh = kCoeff * (h_new - ap_h) + s1_h;
      unsigned vb = tagf(nh, (unsigned)(t + 1) & 511u);  // self-tagged bits
      unsigned pb = __shfl_xor(vb, 16);                  // partner unit's bits
      if ((tid & 31) == 12) {  // g==3,q==0 of even local unit: one per slot
        const int s = w * 16 + (tid >> 5);  // global slot = u/2
        unsigned long long pk = (unsigned long long)vb |
                                ((unsigned long long)pb << 32);
        __hip_atomic_store(mypub + ((t + 1) & 1) * 128 + s, pk, __ATOMIC_RELAXED,
                           __HIP_MEMORY_SCOPE_AGENT);  // remote WGs (IC)
        *(float2*)&hs2[(t + 1) & 1][pidx(2 * s)] =      // own WG (LDS shortcut)
            make_float2(__uint_as_float(vb), __uint_as_float(pb));
      }
      float nc = kCoeff * (c_new - ap_c) + s1_c;
      s1_h = h_new; s1_c = c_new; ap_h = nh; ap_c = nc;
    } else {
      if (g == 0 && q == 0)      out[201326592 + b * 512 + u] = ap_h;        // ap_final h
      else if (g == 1 && q == 0) out[201326592 + b * 512 + 256 + u] = ap_c;  // ap_final c
    }

    // ---- outputs: (y, states_h, states_c) fp32, fire-and-forget ----
    int o = (b * Tn + t) * Hn + u;
    if (q == 0) {
      if (g == 0)      out[o] = h_new;             // y
      else if (g == 2) out[67108864 + o] = h_new;  // states h
      else if (g == 1) out[134217728 + o] = c_new; // states c
    }
    // no trailing barrier: parity dbuf + publish-after-barrier make it safe
  }
}

extern "C" void kernel_launch(void* const* d_in, const int* in_sizes, int n_in,
                              void* d_out, int out_size, void* d_ws, size_t ws_size,
                              hipStream_t stream) {
  const float* x = (const float*)d_in[0];
  const float* W_ih = (const float*)d_in[1];
  const float* W_hh = (const float*)d_in[2];
  const float* b_ih = (const float*)d_in[3];
  const float* b_hh = (const float*)d_in[4];
  float* out = (float*)d_out;
  unsigned long long* pub = (unsigned long long*)d_ws;

  init_ws<<<64, 256, 0, stream>>>((unsigned int*)d_ws);  // reset tags every launch
  apdl_rnn<<<256, 512, 0, stream>>>(x, W_ih, W_hh, b_ih, b_hh, out, pub);
}